// Round 8
// baseline (321.859 us; speedup 1.0000x reference)
//
#include <hip/hip_runtime.h>
#include <math.h>

typedef _Float16 half8 __attribute__((ext_vector_type(8)));
typedef _Float16 half4 __attribute__((ext_vector_type(4)));
typedef float f32x16 __attribute__((ext_vector_type(16)));

constexpr int IN    = 256;
constexpr int NCLS  = 47;
constexpr int HD1   = 188;
constexpr float NEG_SLOPE = 0.2f;
constexpr int ND0 = 50000, ND1 = 10000;

static __device__ __forceinline__ float leaky(float x) {
    return x >= 0.f ? x : NEG_SLOPE * x;
}

__device__ __forceinline__ void gload16(const void* g, void* l) {
    __builtin_amdgcn_global_load_lds((const __attribute__((address_space(1))) void*)g,
                                     (__attribute__((address_space(3))) void*)l, 16, 0, 0);
}

// ---------------- prep: f16 B^T layouts (natural k), folded attn vectors ----------------
__global__ __launch_bounds__(256) void prep_k(
        const float* __restrict__ W0s, const float* __restrict__ W1s,
        const float* __restrict__ W0d, const float* __restrict__ W1d,
        const float* __restrict__ ar0, const float* __restrict__ al1,
        const float* __restrict__ ar1,
        _Float16* __restrict__ B0t, _Float16* __restrict__ B1t,
        float* __restrict__ vr0T, float* __restrict__ vl1T, float* __restrict__ vr1T) {
    int b = blockIdx.x, t = threadIdx.x;
    if (b < 256) {                       // B0t[n][k] = f16 W0s[k][n]
        int id = b * 256 + t;
        int n = id >> 8, k = id & 255;
        B0t[n * 256 + k] = (_Float16)W0s[(size_t)k * 256 + n];
    } else if (b < 448) {                // B1t[n][k] = f16 W1s[k][n] (n<188, pad to 192)
        int id = (b - 256) * 256 + t;
        int n = id >> 8, k = id & 255;
        B1t[n * 256 + k] = (n < HD1) ? (_Float16)W1s[(size_t)k * HD1 + n] : (_Float16)0.f;
    } else if (b == 448) {               // vr0T[h*256+k]
        for (int i = t; i < 1024; i += 256) {
            int h = i >> 8, k = i & 255;
            float s = 0.f;
            for (int d = 0; d < 64; ++d)
                s += W0d[(size_t)k * 256 + h * 64 + d] * ar0[h * 64 + d];
            vr0T[h * 256 + k] = s;
        }
    } else if (b == 449) {               // vl1T[h*256+k]
        for (int i = t; i < 1024; i += 256) {
            int h = i >> 8, k = i & 255;
            float s = 0.f;
            for (int d = 0; d < NCLS; ++d)
                s += W1s[(size_t)k * HD1 + h * NCLS + d] * al1[h * NCLS + d];
            vl1T[h * 256 + k] = s;
        }
    } else {                             // vr1T[h*256+k]
        for (int i = t; i < 1024; i += 256) {
            int h = i >> 8, k = i & 255;
            float s = 0.f;
            for (int d = 0; d < NCLS; ++d)
                s += W1d[(size_t)k * HD1 + h * NCLS + d] * ar1[h * NCLS + d];
            vr1T[h * 256 + k] = s;
        }
    }
}

// ---------------- persistent swapped-operand MFMA GEMM ----------------
// Weights (wave's 32 cols x 256 K, f16) live in 64 VGPRs as the MFMA A-operand.
// x rows are the B-operand: lane l31 = one x-row, staged FULL-ROW-PER-INSTRUCTION
// via global_load_lds into a +16B-row-padded LDS double buffer (linear dest; 4
// rows/bank-quad = optimal). One barrier per 32-row tile; stage(t+1) overlaps
// compute(t). D layout: col(l31)=x-row, row(q)=wcol -> z stores are 4x half4
// per lane into the lane's own row; el is lane-local (reduced via one shfl_xor).
template <bool AHALF, int NWC, bool FEL>
__global__ __launch_bounds__(512, 4) void gemmk(const void* __restrict__ Av,
        const _Float16* __restrict__ Bt, _Float16* __restrict__ Z,
        const float* __restrict__ al, float* __restrict__ el, int M, int ntiles) {
    constexpr int ABYTES = AHALF ? 16 * 1040 : 32 * 1040;
    __shared__ __align__(16) char As[2][ABYTES];
    __shared__ float elp[2][8][32];
    __shared__ float alds[256];
    const int t = threadIdx.x, l = t & 63, w = t >> 6;
    const int l31 = l & 31, hi = l >> 5;
    const int G = gridDim.x;

    if (FEL && t < 256) alds[t] = al[t];

    // weights -> regs (wk[ks] = Bt[wcol][ks*16 + hi*8 .. +8])
    half8 wk[16];
    {
        int wc = (w < NWC) ? w * 32 + l31 : 0;
        const _Float16* bp = Bt + (size_t)wc * 256 + hi * 8;
#pragma unroll
        for (int ks = 0; ks < 16; ++ks) wk[ks] = *(const half8*)(bp + ks * 16);
    }

    auto stage = [&](int buf, int tile) {
        if constexpr (AHALF) {
#pragma unroll
            for (int i = 0; i < 2; ++i) {
                int pr = w * 2 + i;                 // row-pair 0..15
                int row = tile * 32 + pr * 2 + hi;  // lanes 0-31 row, 32-63 row+1
                if (row >= M) row = M - 1;
                gload16((const _Float16*)Av + (size_t)row * 256 + l31 * 8,
                        As[buf] + pr * 1040);
            }
        } else {
#pragma unroll
            for (int i = 0; i < 4; ++i) {
                int r = w * 4 + i;                  // row 0..31
                int row = tile * 32 + r;
                if (row >= M) row = M - 1;
                gload16((const float*)Av + (size_t)row * 256 + l * 4,
                        As[buf] + r * 1040);
            }
        }
    };

    int tile0 = blockIdx.x;
    stage(0, tile0);
    asm volatile("s_waitcnt vmcnt(0)" ::: "memory");
    __syncthreads();

    int buf = 0;
    for (int tile = tile0; tile < ntiles; tile += G) {
        int nxt = tile + G;
        if (nxt < ntiles) stage(buf ^ 1, nxt);

        if (w < NWC) {
            f32x16 acc;
#pragma unroll
            for (int e = 0; e < 16; ++e) acc[e] = 0.f;
#pragma unroll
            for (int ks = 0; ks < 16; ++ks) {
                half8 bf;
                if constexpr (AHALF) {
                    bf = *(const half8*)(As[buf] + (l31 >> 1) * 1040 + (l31 & 1) * 512
                                         + ks * 32 + hi * 16);
                } else {
                    const char* ab = As[buf] + l31 * 1040 + ks * 64 + hi * 32;
                    float4 f0 = *(const float4*)ab;
                    float4 f1 = *(const float4*)(ab + 16);
                    bf[0] = (_Float16)f0.x; bf[1] = (_Float16)f0.y;
                    bf[2] = (_Float16)f0.z; bf[3] = (_Float16)f0.w;
                    bf[4] = (_Float16)f1.x; bf[5] = (_Float16)f1.y;
                    bf[6] = (_Float16)f1.z; bf[7] = (_Float16)f1.w;
                }
                acc = __builtin_amdgcn_mfma_f32_32x32x16_f16(wk[ks], bf, acc, 0, 0, 0);
            }
            int xrow = tile * 32 + l31;
            if (xrow < M) {
#pragma unroll
                for (int g = 0; g < 4; ++g) {
                    half4 hv;
                    hv[0] = (_Float16)acc[g * 4 + 0]; hv[1] = (_Float16)acc[g * 4 + 1];
                    hv[2] = (_Float16)acc[g * 4 + 2]; hv[3] = (_Float16)acc[g * 4 + 3];
                    *(half4*)(Z + (size_t)xrow * (NWC * 32) + w * 32 + g * 8 + hi * 4) = hv;
                }
            }
            if constexpr (FEL) {
                float s = 0.f;
#pragma unroll
                for (int q = 0; q < 16; ++q)
                    s += acc[q] * alds[w * 32 + (q & 3) + 8 * (q >> 2) + 4 * hi];
                s += __shfl_xor(s, 32);
                if (hi == 0) elp[buf][w][l31] = s;
            }
        }
        asm volatile("s_waitcnt vmcnt(0)" ::: "memory");
        __syncthreads();
        if constexpr (FEL) {
            if (w < 4 && hi == 0) {
                int xrow = tile * 32 + l31;
                if (xrow < M)
                    el[(size_t)xrow * 4 + w] =
                        elp[buf][2 * w][l31] + elp[buf][2 * w + 1][l31];
            }
        }
        buf ^= 1;
    }
}

// er[m,h] = x[m,:] @ vrT[h,:] (fp32 x); one wave per row (full-row reads)
__global__ __launch_bounds__(256) void gemv_er_f32(const float* __restrict__ A,
        const float* __restrict__ vrT, float* __restrict__ er, int M) {
    int wv = threadIdx.x >> 6, lane = threadIdx.x & 63;
    int row = blockIdx.x * 4 + wv;
    if (row >= M) return;
    float4 xa = *(const float4*)(A + (size_t)row * IN + lane * 4);
    float s[4];
#pragma unroll
    for (int h = 0; h < 4; ++h) {
        float4 v = *(const float4*)(vrT + h * IN + lane * 4);
        s[h] = xa.x * v.x + xa.y * v.y + xa.z * v.z + xa.w * v.w;
    }
#pragma unroll
    for (int off = 32; off; off >>= 1)
#pragma unroll
        for (int h = 0; h < 4; ++h) s[h] += __shfl_xor(s[h], off);
    if (lane == 0) *(float4*)(er + (size_t)row * 4) = make_float4(s[0], s[1], s[2], s[3]);
}

// el (all rows) + er (rows < Mr) from f16 h, natural layout
__global__ __launch_bounds__(256) void gemv_lr_f16(const _Float16* __restrict__ A,
        const float* __restrict__ vlT, const float* __restrict__ vrT,
        float* __restrict__ el, float* __restrict__ er, int M, int Mr) {
    int wv = threadIdx.x >> 6, lane = threadIdx.x & 63;
    int row = blockIdx.x * 4 + wv;
    if (row >= M) return;
    half4 ah = *(const half4*)(A + (size_t)row * IN + lane * 4);
    float a0 = (float)ah[0], a1 = (float)ah[1], a2 = (float)ah[2], a3 = (float)ah[3];
    float sl[4], sr[4];
#pragma unroll
    for (int h = 0; h < 4; ++h) {
        float4 v = *(const float4*)(vlT + h * IN + lane * 4);
        sl[h] = a0 * v.x + a1 * v.y + a2 * v.z + a3 * v.w;
        float4 u = *(const float4*)(vrT + h * IN + lane * 4);
        sr[h] = a0 * u.x + a1 * u.y + a2 * u.z + a3 * u.w;
    }
#pragma unroll
    for (int off = 32; off; off >>= 1)
#pragma unroll
        for (int h = 0; h < 4; ++h) {
            sl[h] += __shfl_xor(sl[h], off);
            sr[h] += __shfl_xor(sr[h], off);
        }
    if (lane == 0) {
        *(float4*)(el + (size_t)row * 4) = make_float4(sl[0], sl[1], sl[2], sl[3]);
        if (row < Mr)
            *(float4*)(er + (size_t)row * 4) = make_float4(sr[0], sr[1], sr[2], sr[3]);
    }
}

// combined histogram over both layers' edges (counts = [ND0 | ND1])
__global__ void hist2_k(const int* __restrict__ dst0, int E0,
                        const int* __restrict__ dst1, int E1, int* __restrict__ counts) {
    int i = blockIdx.x * blockDim.x + threadIdx.x;
    if (i < E0) atomicAdd(&counts[dst0[i]], 1);
    else if (i < E0 + E1) atomicAdd(&counts[ND0 + dst1[i - E0]], 1);
}

// ---- 3-kernel parallel exclusive scan ----
__global__ __launch_bounds__(256) void scan1_k(const int* __restrict__ counts, int n,
                                               int* __restrict__ part) {
    __shared__ int ws[4];
    int i = blockIdx.x * 256 + threadIdx.x;
    int lane = threadIdx.x & 63, wv = threadIdx.x >> 6;
    int s = (i < n) ? counts[i] : 0;
#pragma unroll
    for (int off = 32; off; off >>= 1) s += __shfl_xor(s, off);
    if (lane == 0) ws[wv] = s;
    __syncthreads();
    if (threadIdx.x == 0) part[blockIdx.x] = ws[0] + ws[1] + ws[2] + ws[3];
}

__global__ __launch_bounds__(256) void scan2_k(int* __restrict__ part, int nb) {
    __shared__ int ws[4];
    int tid = threadIdx.x, lane = tid & 63, wv = tid >> 6;
    int v = (tid < nb) ? part[tid] : 0;
    int x = v;
#pragma unroll
    for (int off = 1; off < 64; off <<= 1) {
        int u = __shfl_up(x, off);
        if (lane >= off) x += u;
    }
    if (lane == 63) ws[wv] = x;
    __syncthreads();
    int base = 0;
    for (int k = 0; k < wv; ++k) base += ws[k];
    if (tid < nb) part[tid] = base + x - v;
}

__global__ __launch_bounds__(256) void scan3_k(const int* __restrict__ counts, int n,
        const int* __restrict__ part, int* __restrict__ offsets, int* __restrict__ cursor) {
    __shared__ int ws[4];
    int i = blockIdx.x * 256 + threadIdx.x;
    int lane = threadIdx.x & 63, wv = threadIdx.x >> 6;
    int v = (i < n) ? counts[i] : 0;
    int x = v;
#pragma unroll
    for (int off = 1; off < 64; off <<= 1) {
        int u = __shfl_up(x, off);
        if (lane >= off) x += u;
    }
    if (lane == 63) ws[wv] = x;
    __syncthreads();
    int base = part[blockIdx.x];
    for (int k = 0; k < wv; ++k) base += ws[k];
    int off_ = base + x - v;
    if (i < n) { offsets[i] = off_; cursor[i] = off_; }
    if (i == n - 1) offsets[n] = off_ + v;
}

__global__ void scatter2_k(const int* __restrict__ src0, const int* __restrict__ dst0, int E0,
                           const int* __restrict__ src1, const int* __restrict__ dst1, int E1,
                           int* __restrict__ cursor, int* __restrict__ ssrc) {
    int i = blockIdx.x * blockDim.x + threadIdx.x;
    if (i < E0) {
        int p = atomicAdd(&cursor[dst0[i]], 1);
        ssrc[p] = src0[i];
    } else if (i < E0 + E1) {
        int j = i - E0;
        int p = atomicAdd(&cursor[ND0 + dst1[j]], 1);
        ssrc[p] = src1[j];
    }
}

// Layer-0 aggregation: natural z f16 [*,256]; 4 waves/block, edge loop x4 unroll
__global__ __launch_bounds__(256) void agg_l0(const int* __restrict__ ssrc,
        const int* __restrict__ offs, const float* __restrict__ el,
        const float* __restrict__ er, const _Float16* __restrict__ z,
        const float* __restrict__ bias, _Float16* __restrict__ h, int nd) {
    int wv = threadIdx.x >> 6, lane = threadIdx.x & 63;
    int d = blockIdx.x * 4 + wv;
    if (d >= nd) return;
    int head = lane >> 4;
    int beg = offs[d], end = offs[d + 1];
    float erh = er[(size_t)d * 4 + head];
    float ax = 0, ay = 0, az = 0, aw = 0, ssum = 0;
    for (int j0 = beg; j0 < end; j0 += 64) {
        int nn = min(64, end - j0);
        int myidx = (lane < nn) ? ssrc[j0 + lane] : 0;
        int j = 0;
        for (; j + 4 <= nn; j += 4) {
            int s0 = __shfl(myidx, j),     s1 = __shfl(myidx, j + 1);
            int s2 = __shfl(myidx, j + 2), s3 = __shfl(myidx, j + 3);
            float e0 = el[(size_t)s0 * 4 + head], e1 = el[(size_t)s1 * 4 + head];
            float e2 = el[(size_t)s2 * 4 + head], e3 = el[(size_t)s3 * 4 + head];
            half4 zv0 = *(const half4*)(z + (size_t)s0 * 256 + lane * 4);
            half4 zv1 = *(const half4*)(z + (size_t)s1 * 256 + lane * 4);
            half4 zv2 = *(const half4*)(z + (size_t)s2 * 256 + lane * 4);
            half4 zv3 = *(const half4*)(z + (size_t)s3 * 256 + lane * 4);
            float w0 = __expf(leaky(e0 + erh)), w1 = __expf(leaky(e1 + erh));
            float w2 = __expf(leaky(e2 + erh)), w3 = __expf(leaky(e3 + erh));
            ssum += (w0 + w1) + (w2 + w3);
            ax += w0 * (float)zv0[0] + w1 * (float)zv1[0] + w2 * (float)zv2[0] + w3 * (float)zv3[0];
            ay += w0 * (float)zv0[1] + w1 * (float)zv1[1] + w2 * (float)zv2[1] + w3 * (float)zv3[1];
            az += w0 * (float)zv0[2] + w1 * (float)zv1[2] + w2 * (float)zv2[2] + w3 * (float)zv3[2];
            aw += w0 * (float)zv0[3] + w1 * (float)zv1[3] + w2 * (float)zv2[3] + w3 * (float)zv3[3];
        }
        for (; j < nn; ++j) {
            int s = __shfl(myidx, j);
            float e = el[(size_t)s * 4 + head] + erh;
            float wgt = __expf(leaky(e));
            ssum += wgt;
            half4 zv = *(const half4*)(z + (size_t)s * 256 + lane * 4);
            ax += wgt * (float)zv[0]; ay += wgt * (float)zv[1];
            az += wgt * (float)zv[2]; aw += wgt * (float)zv[3];
        }
    }
    float inv = ssum > 0.f ? 1.f / ssum : 0.f;
    const float* b = bias + lane * 4;
    half4 o;
    o[0] = (_Float16)fmaxf(ax * inv + b[0], 0.f);
    o[1] = (_Float16)fmaxf(ay * inv + b[1], 0.f);
    o[2] = (_Float16)fmaxf(az * inv + b[2], 0.f);
    o[3] = (_Float16)fmaxf(aw * inv + b[3], 0.f);
    *(half4*)(h + (size_t)d * 256 + lane * 4) = o;
}

// Layer-1 aggregation (z1 f16 [*,192]) + fused head-mean + log_softmax
__global__ __launch_bounds__(256) void agg_l1f(const int* __restrict__ ssrc,
        const int* __restrict__ offs, const float* __restrict__ el,
        const float* __restrict__ er, const _Float16* __restrict__ z,
        const float* __restrict__ bias, float* __restrict__ y, int nd) {
    __shared__ float ro[4][192];
    int wv = threadIdx.x >> 6, lane = threadIdx.x & 63;
    int d = blockIdx.x * 4 + wv;
    if (d >= nd) return;
    int beg = offs[ND0 + d], end = offs[ND0 + d + 1];
    float4 er4 = *(const float4*)(er + (size_t)d * 4);
    const int f0 = lane, f1 = lane + 64, f2 = lane + 128;
    const int h0 = f0 / NCLS, h1 = f1 / NCLS;
    const bool has2 = f2 < HD1;
    const int h2 = has2 ? f2 / NCLS : 3;
    float a0 = 0, a1 = 0, a2 = 0;
    float s0 = 0, s1 = 0, s2 = 0, s3 = 0;
    for (int j0 = beg; j0 < end; j0 += 64) {
        int nn = min(64, end - j0);
        int myidx = (lane < nn) ? ssrc[j0 + lane] : 0;
        int j = 0;
        for (; j + 2 <= nn; j += 2) {
            int sa_ = __shfl(myidx, j), sb_ = __shfl(myidx, j + 1);
            float4 ea = *(const float4*)(el + (size_t)sa_ * 4);
            float4 eb = *(const float4*)(el + (size_t)sb_ * 4);
            const _Float16* za = z + (size_t)sa_ * 192;
            const _Float16* zb = z + (size_t)sb_ * 192;
            float za0 = (float)za[f0], za1 = (float)za[f1], za2 = has2 ? (float)za[f2] : 0.f;
            float zb0 = (float)zb[f0], zb1 = (float)zb[f1], zb2 = has2 ? (float)zb[f2] : 0.f;
            float wa0 = __expf(leaky(ea.x + er4.x)), wa1 = __expf(leaky(ea.y + er4.y));
            float wa2 = __expf(leaky(ea.z + er4.z)), wa3 = __expf(leaky(ea.w + er4.w));
            float wb0 = __expf(leaky(eb.x + er4.x)), wb1 = __expf(leaky(eb.y + er4.y));
            float wb2 = __expf(leaky(eb.z + er4.z)), wb3 = __expf(leaky(eb.w + er4.w));
            s0 += wa0 + wb0; s1 += wa1 + wb1; s2 += wa2 + wb2; s3 += wa3 + wb3;
            a0 += (h0 == 0 ? wa0 : h0 == 1 ? wa1 : h0 == 2 ? wa2 : wa3) * za0
                + (h0 == 0 ? wb0 : h0 == 1 ? wb1 : h0 == 2 ? wb2 : wb3) * zb0;
            a1 += (h1 == 0 ? wa0 : h1 == 1 ? wa1 : h1 == 2 ? wa2 : wa3) * za1
                + (h1 == 0 ? wb0 : h1 == 1 ? wb1 : h1 == 2 ? wb2 : wb3) * zb1;
            if (has2)
                a2 += (h2 == 0 ? wa0 : h2 == 1 ? wa1 : h2 == 2 ? wa2 : wa3) * za2
                    + (h2 == 0 ? wb0 : h2 == 1 ? wb1 : h2 == 2 ? wb2 : wb3) * zb2;
        }
        for (; j < nn; ++j) {
            int s = __shfl(myidx, j);
            float4 e4 = *(const float4*)(el + (size_t)s * 4);
            float w0 = __expf(leaky(e4.x + er4.x));
            float w1 = __expf(leaky(e4.y + er4.y));
            float w2 = __expf(leaky(e4.z + er4.z));
            float w3 = __expf(leaky(e4.w + er4.w));
            s0 += w0; s1 += w1; s2 += w2; s3 += w3;
            const _Float16* zr = z + (size_t)s * 192;
            a0 += (h0 == 0 ? w0 : h0 == 1 ? w1 : h0 == 2 ? w2 : w3) * (float)zr[f0];
            a1 += (h1 == 0 ? w0 : h1 == 1 ? w1 : h1 == 2 ? w2 : w3) * (float)zr[f1];
            if (has2) a2 += (h2 == 0 ? w0 : h2 == 1 ? w1 : h2 == 2 ? w2 : w3) * (float)zr[f2];
        }
    }
    float sa = h0 == 0 ? s0 : h0 == 1 ? s1 : h0 == 2 ? s2 : s3;
    float sb = h1 == 0 ? s0 : h1 == 1 ? s1 : h1 == 2 ? s2 : s3;
    float sc = h2 == 0 ? s0 : h2 == 1 ? s1 : h2 == 2 ? s2 : s3;
    ro[wv][f0] = a0 * (sa > 0.f ? 1.f / sa : 0.f) + bias[f0];
    ro[wv][f1] = a1 * (sb > 0.f ? 1.f / sb : 0.f) + bias[f1];
    if (has2) ro[wv][f2] = a2 * (sc > 0.f ? 1.f / sc : 0.f) + bias[f2];
    asm volatile("s_waitcnt lgkmcnt(0)" ::: "memory");
    __builtin_amdgcn_sched_barrier(0);
    float vv = 0.f, v = -INFINITY;
    if (lane < NCLS) {
        vv = 0.25f * (ro[wv][lane] + ro[wv][lane + NCLS] +
                      ro[wv][lane + 2 * NCLS] + ro[wv][lane + 3 * NCLS]);
        v = vv;
    }
    float mx = v;
#pragma unroll
    for (int off = 32; off; off >>= 1) mx = fmaxf(mx, __shfl_xor(mx, off));
    float pp = (lane < NCLS) ? __expf(vv - mx) : 0.f;
    float sum = pp;
#pragma unroll
    for (int off = 32; off; off >>= 1) sum += __shfl_xor(sum, off);
    if (lane < NCLS) y[(size_t)d * NCLS + lane] = vv - mx - logf(sum);
}

extern "C" void kernel_launch(void* const* d_in, const int* in_sizes, int n_in,
                              void* d_out, int out_size, void* d_ws, size_t ws_size,
                              hipStream_t stream) {
    const float* x    = (const float*)d_in[0];
    const int*   src0 = (const int*)d_in[1];
    const int*   dst0 = (const int*)d_in[2];
    const int*   src1 = (const int*)d_in[3];
    const int*   dst1 = (const int*)d_in[4];
    const float* W0s  = (const float*)d_in[7];
    const float* W0d  = (const float*)d_in[8];
    const float* al0  = (const float*)d_in[9];
    const float* ar0  = (const float*)d_in[10];
    const float* b0   = (const float*)d_in[11];
    const float* W1s  = (const float*)d_in[12];
    const float* W1d  = (const float*)d_in[13];
    const float* al1  = (const float*)d_in[14];
    const float* ar1  = (const float*)d_in[15];
    const float* b1   = (const float*)d_in[16];
    const int E0 = in_sizes[1], E1 = in_sizes[3];
    const int NS0 = in_sizes[0] / IN;

    char* p = (char*)d_ws;
    auto take = [&](size_t bytes) {
        char* r = p;
        p += (bytes + 255) & ~(size_t)255;
        return r;
    };
    _Float16* z0   = (_Float16*)take((size_t)NS0 * 256 * 2);
    _Float16* h    = (_Float16*)take((size_t)ND0 * 256 * 2);
    _Float16* z1   = (_Float16*)take((size_t)ND0 * 192 * 2);
    float*    el0  = (float*)take((size_t)NS0 * 4 * 4);
    float*    er0  = (float*)take((size_t)ND0 * 4 * 4);
    float*    el1  = (float*)take((size_t)ND0 * 4 * 4);
    float*    er1  = (float*)take((size_t)ND1 * 4 * 4);
    _Float16* B0t  = (_Float16*)take((size_t)256 * 256 * 2);
    _Float16* B1t  = (_Float16*)take((size_t)192 * 256 * 2);
    float*    vr0T = (float*)take(4 * 256 * 4);
    float*    vl1T = (float*)take(4 * 256 * 4);
    float*    vr1T = (float*)take(4 * 256 * 4);
    const int NDT = ND0 + ND1;
    int* counts = (int*)take((size_t)NDT * 4);
    int* offs   = (int*)take((size_t)(NDT + 1) * 4);
    int* cur    = (int*)take((size_t)NDT * 4);
    int* ss     = (int*)take((size_t)(E0 + E1) * 4);
    int* part   = (int*)take(256 * 4);

    const int NB = (NDT + 255) / 256;
    const int NT0 = (NS0 + 31) / 32, NT1 = (ND0 + 31) / 32;
    const int G0 = NT0 < 512 ? NT0 : 512, G1 = NT1 < 512 ? NT1 : 512;

    hipMemsetAsync(counts, 0, (size_t)NDT * 4, stream);

    prep_k<<<451, 256, 0, stream>>>(W0s, W1s, W0d, W1d, ar0, al1, ar1,
                                    B0t, B1t, vr0T, vl1T, vr1T);
    hist2_k<<<(E0 + E1 + 255) / 256, 256, 0, stream>>>(dst0, E0, dst1, E1, counts);
    scan1_k<<<NB, 256, 0, stream>>>(counts, NDT, part);
    scan2_k<<<1, 256, 0, stream>>>(part, NB);
    scan3_k<<<NB, 256, 0, stream>>>(counts, NDT, part, offs, cur);
    scatter2_k<<<(E0 + E1 + 255) / 256, 256, 0, stream>>>(src0, dst0, E0, src1, dst1, E1,
                                                          cur, ss);

    // ---- layer 0 ----
    gemmk<false, 8, true><<<G0, 512, 0, stream>>>(
        (const void*)x, B0t, z0, al0, el0, NS0, NT0);
    gemv_er_f32<<<(ND0 + 3) / 4, 256, 0, stream>>>(x, vr0T, er0, ND0);
    agg_l0<<<(ND0 + 3) / 4, 256, 0, stream>>>(ss, offs, el0, er0, z0, b0, h, ND0);

    // ---- layer 1 ----
    gemmk<true, 6, false><<<G1, 512, 0, stream>>>(
        (const void*)h, B1t, z1, nullptr, nullptr, ND0, NT1);
    gemv_lr_f16<<<(ND0 + 3) / 4, 256, 0, stream>>>(h, vl1T, vr1T, el1, er1, ND0, ND1);
    agg_l1f<<<(ND1 + 3) / 4, 256, 0, stream>>>(ss, offs, el1, er1, z1, b1,
                                               (float*)d_out, ND1);
}